// Round 6
// baseline (633.766 us; speedup 1.0000x reference)
//
#include <hip/hip_runtime.h>
#include <math.h>

// ============================ RELAY LEDGER =================================
// FACTS (hardware-proven, don't re-derive)
//  F1 clocks vary per container hold (same src: 609 vs 1079 us). Compare
//     SHARES within a run, never absolute us across runs.
//  F2 absmax = 0.00390625 in every passing run (f32 AND split-bf16) ->
//     split-bf16 (hh+hl+lh, err ~2^-16) is numerically free. Do NOT drop
//     to plain bf16 for hidden layers.
//  F3 PROVEN mfma_f32_16x16x32_bf16 layouts (R4/R5 end-to-end):
//     A/B frag: elem j of lane = M[row|col = lane&15][k = (lane>>4)*8 + j]
//     C/D: col = lane&15, row = (lane>>4)*4 + reg.
//     => A-frag is 16 CONTIGUOUS bytes at row*K*2 + (lane>>4)*16 (global-loadable).
//  F4 R5 shares: trans ~150-165us (30%), MfmaUtil 24% (=594TF effective),
//     VALU 30%, HBM 20-24%, LDS-conflict 2.17e7. Blocks all < trans now.
//  F5 kernel id by LDS_Block_Size (1024-gran) when names collide.
// DECISIONS
//  D3 ws map unchanged (peak 125,829,120 B proven). Do NOT exceed: adding
//     a pre-split-W global buffer (3.6MB) does NOT fit alongside a+zz
//     (129.5MB > proven) — that's why W is split in-kernel to LDS.
//  D4 block_mfma: x frags read direct from global (never staged); weights
//     hoisted to regs per ch; V-neighbor via shfl; pad rows masked. SAFE.
//  D6 trans v3 (this round): A frags DIRECT from global (u16x8/lane, 16
//     rows x 64B per instr -> L2/L3 gather; A reused 13x via L3). LDS only
//     holds W 64x32 tile (hi/lo, dbuf, 20.5KB), 1 sync/iter, unroll-2 for
//     static reg buffers. RISK: if gather thrashes (dur up, hbm up), revert
//     to staged-A with XOR swizzle.
//  D7 dec3+fk fused (1 thread = 1 graph, rolling 3-row window, clamped
//     node+1 read masked by has2).
// NEXT: if trans ~<90us and blocks surface: block_mfma epilogue VALU (edge
//     attr) is the next shave; else micro-tune trans (BM=256, setprio).
// ===========================================================================

constexpr int G_NUM = 8192;
constexpr int JS = 17;
constexpr int JT = 13;
constexpr int N_ENC = 2 * G_NUM * JS;
constexpr int N_DEC = 2 * G_NUM * JT;
constexpr int G2 = 2 * G_NUM;
constexpr int HN = G_NUM * JT;
constexpr int K_TR = JS * 64;            // 1088
constexpr int N_TR = JT * 64;            // 832

typedef unsigned short u16;
typedef u16   u16x8 __attribute__((ext_vector_type(8)));
typedef u16   u16x4 __attribute__((ext_vector_type(4)));
typedef float f32x4 __attribute__((ext_vector_type(4)));
typedef __bf16 bf16x8 __attribute__((ext_vector_type(8)));

__device__ __forceinline__ float lrelu(float v) { return v > 0.f ? v : 0.01f * v; }
__device__ __forceinline__ u16 f2bf(float f) {
    unsigned u = __float_as_uint(f);
    u += 0x7fff + ((u >> 16) & 1);
    return (u16)(u >> 16);
}
__device__ __forceinline__ float bf2f(u16 h) { return __uint_as_float((unsigned)h << 16); }

// ---------------------------------------------------------------------------
// block_mfma: whole SpatialBasicBlock on matrix cores (split-bf16 in/out).
template<int K_MM, int C_IN_W, int C_OUT, int C_E, int J, int G, bool TAIL>
__global__ __launch_bounds__(256)
void block_mfma(const u16* __restrict__ xHi, const u16* __restrict__ xLo,
                const float* __restrict__ eaA, const float* __restrict__ eaB, int g_half,
                const float* __restrict__ lowv, const float* __restrict__ upv,
                const float* __restrict__ Wl, const float* __restrict__ bl,
                const float* __restrict__ Wu, const float* __restrict__ bu,
                u16* __restrict__ outHi, u16* __restrict__ outLo)
{
    constexpr int ROWS = G * J;
    constexpr int F = (ROWS + 15) / 16;
    constexpr int NCH = C_OUT / 16;
    constexpr int KF = K_MM / 32;
    constexpr int KPAD = K_MM + 8;
    constexpr int EAS = 2 * (J - 1) * C_E;
    constexpr int CTOT = 2 * C_IN_W + C_E;
    constexpr int CW = (C_IN_W < K_MM) ? C_IN_W : K_MM;
    constexpr int WGG = 4 * G;

    __shared__ __align__(16) u16 sWH[3 * C_OUT * KPAD], sWL[3 * C_OUT * KPAD];
    __shared__ float sEA[WGG * EAS];
    __shared__ float sWe[C_OUT * C_E];
    __shared__ float sBl[C_OUT], sBu[C_OUT];
    __shared__ float sTl[TAIL ? 6 * C_OUT : 1];
    __shared__ float sLow[TAIL ? WGG * J : 1], sUpp[TAIL ? WGG * J : 1];

    const int t = threadIdx.x;
    const int g0 = blockIdx.x * WGG;

    for (int i = t; i < 3 * C_OUT * K_MM; i += 256) {
        const int ch = i / K_MM, k = i % K_MM;
        const int p = ch / C_OUT, o = ch % C_OUT;
        float v = 0.f;
        if (k < CW) {
            if (p == 0)      v = Wl[o * CTOT + k];
            else if (p == 1) v = Wl[o * CTOT + C_IN_W + k];
            else             v = Wu[o * C_IN_W + k];
        }
        const u16 h = f2bf(v);
        sWH[ch * KPAD + k] = h;
        sWL[ch * KPAD + k] = f2bf(v - bf2f(h));
    }
    for (int i = t; i < WGG * EAS; i += 256) {
        const int lg = i / EAS, r = i % EAS;
        const int g = g0 + lg;
        sEA[i] = (g < g_half) ? eaA[(size_t)g * EAS + r]
                              : eaB[(size_t)(g - g_half) * EAS + r];
    }
    for (int i = t; i < C_OUT * C_E; i += 256)
        sWe[i] = Wl[(i / C_E) * CTOT + 2 * C_IN_W + (i % C_E)];
    if (t < C_OUT) { sBl[t] = bl[t]; sBu[t] = bu[t]; }
    if constexpr (TAIL) {
        if (t < C_OUT) {
            sTl[t * 6 + 0] = Wl[t * CTOT + K_MM];
            sTl[t * 6 + 1] = Wl[t * CTOT + K_MM + 1];
            sTl[t * 6 + 2] = Wl[t * CTOT + C_IN_W + K_MM];
            sTl[t * 6 + 3] = Wl[t * CTOT + C_IN_W + K_MM + 1];
            sTl[t * 6 + 4] = Wu[t * C_IN_W + K_MM];
            sTl[t * 6 + 5] = Wu[t * C_IN_W + K_MM + 1];
        }
        for (int i = t; i < WGG * J; i += 256) {
            const int lg = i / J, j = i % J;
            const int g = g0 + lg;
            const int ge = (g < g_half) ? g : g - g_half;
            sLow[i] = lowv[ge * J + j];
            sUpp[i] = upv[ge * J + j];
        }
    }
    __syncthreads();

    const int wv = t >> 6, lane = t & 63;
    const int col = lane & 15, kg = lane >> 4;
    const size_t baseNode = (size_t)(blockIdx.x * 4 + wv) * ROWS;
    const int lgB = wv * G;

    for (int ch = 0; ch < NCH; ++ch) {
        const int o = ch * 16 + col;
        bf16x8 wUh[KF], wUl[KF], wVh[KF], wVl[KF], wPh[KF], wPl[KF];
        #pragma unroll
        for (int kf = 0; kf < KF; ++kf) {
            wUh[kf] = *(const bf16x8*)&sWH[(0 * C_OUT + o) * KPAD + kf * 32 + kg * 8];
            wUl[kf] = *(const bf16x8*)&sWL[(0 * C_OUT + o) * KPAD + kf * 32 + kg * 8];
            wVh[kf] = *(const bf16x8*)&sWH[(1 * C_OUT + o) * KPAD + kf * 32 + kg * 8];
            wVl[kf] = *(const bf16x8*)&sWL[(1 * C_OUT + o) * KPAD + kf * 32 + kg * 8];
            wPh[kf] = *(const bf16x8*)&sWH[(2 * C_OUT + o) * KPAD + kf * 32 + kg * 8];
            wPl[kf] = *(const bf16x8*)&sWL[(2 * C_OUT + o) * KPAD + kf * 32 + kg * 8];
        }
        float we[C_E];
        #pragma unroll
        for (int k = 0; k < C_E; ++k) we[k] = sWe[o * C_E + k];
        const float blo = sBl[o], buo = sBu[o];
        float tl0 = 0, tl1 = 0, tl2 = 0, tl3 = 0, tl4 = 0, tl5 = 0;
        if constexpr (TAIL) {
            tl0 = sTl[o * 6 + 0]; tl1 = sTl[o * 6 + 1]; tl2 = sTl[o * 6 + 2];
            tl3 = sTl[o * 6 + 3]; tl4 = sTl[o * 6 + 4]; tl5 = sTl[o * 6 + 5];
        }

        f32x4 Vpp = {0,0,0,0}, Vp = {0,0,0,0};
        f32x4 Up = {0,0,0,0}, Pp = {0,0,0,0};
        #pragma unroll
        for (int f = 0; f <= F; ++f) {
            f32x4 Vc = {0,0,0,0}, Uc = {0,0,0,0}, Pc = {0,0,0,0};
            if (f < F) {
                const int nrow = f * 16 + col;
                const size_t nd = baseNode + (nrow < ROWS ? nrow : ROWS - 1);
                #pragma unroll
                for (int kf = 0; kf < KF; ++kf) {
                    const bf16x8 aH = *(const bf16x8*)&xHi[nd * K_MM + kf * 32 + kg * 8];
                    const bf16x8 aL = *(const bf16x8*)&xLo[nd * K_MM + kf * 32 + kg * 8];
                    Vc = __builtin_amdgcn_mfma_f32_16x16x32_bf16(aH, wVh[kf], Vc, 0, 0, 0);
                    Vc = __builtin_amdgcn_mfma_f32_16x16x32_bf16(aH, wVl[kf], Vc, 0, 0, 0);
                    Vc = __builtin_amdgcn_mfma_f32_16x16x32_bf16(aL, wVh[kf], Vc, 0, 0, 0);
                    Uc = __builtin_amdgcn_mfma_f32_16x16x32_bf16(aH, wUh[kf], Uc, 0, 0, 0);
                    Uc = __builtin_amdgcn_mfma_f32_16x16x32_bf16(aH, wUl[kf], Uc, 0, 0, 0);
                    Uc = __builtin_amdgcn_mfma_f32_16x16x32_bf16(aL, wUh[kf], Uc, 0, 0, 0);
                    Pc = __builtin_amdgcn_mfma_f32_16x16x32_bf16(aH, wPh[kf], Pc, 0, 0, 0);
                    Pc = __builtin_amdgcn_mfma_f32_16x16x32_bf16(aH, wPl[kf], Pc, 0, 0, 0);
                    Pc = __builtin_amdgcn_mfma_f32_16x16x32_bf16(aL, wPh[kf], Pc, 0, 0, 0);
                }
            }
            if (f >= 1) {
                const int fm = f - 1;
                const float vL0a = __shfl(Vpp[3], 48 + col);
                const float vL0b = __shfl(Vp[3], (lane - 16) & 63);
                const float vL0 = (kg == 0) ? vL0a : vL0b;
                const float vR3a = __shfl(Vc[0], col);
                const float vR3b = __shfl(Vp[0], (lane + 16) & 63);
                const float vR3 = (kg == 3) ? vR3a : vR3b;
                #pragma unroll
                for (int r = 0; r < 4; ++r) {
                    const int row = fm * 16 + kg * 4 + r;
                    const bool valid = row < ROWS;
                    const int jpos = row % J;
                    int gl = row / J; if (gl > G - 1) gl = G - 1;
                    const int lg = lgB + gl;
                    const bool h1m = valid && (jpos > 0);
                    const bool h2m = valid && (jpos < J - 1);
                    const int jm = jpos > 0 ? jpos - 1 : 0;
                    float e1 = 0.f, e2 = 0.f;
                    #pragma unroll
                    for (int k = 0; k < C_E; ++k) {
                        e1 = fmaf(we[k], sEA[lg * EAS + jm * C_E + k], e1);
                        e2 = fmaf(we[k], sEA[lg * EAS + (J - 1 + jpos) * C_E + k], e2);
                    }
                    float vL = (r == 0) ? vL0 : Vp[r - 1];
                    float vR = (r == 3) ? vR3 : Vp[r + 1];
                    float u = Up[r], p = Pp[r];
                    if constexpr (TAIL) {
                        const int jp = jpos < J - 1 ? jpos + 1 : J - 1;
                        u = fmaf(tl0, sLow[lg * J + jpos], u);
                        u = fmaf(tl1, sUpp[lg * J + jpos], u);
                        p = fmaf(tl4, sLow[lg * J + jpos], p);
                        p = fmaf(tl5, sUpp[lg * J + jpos], p);
                        vL = fmaf(tl2, sLow[lg * J + jm], vL);
                        vL = fmaf(tl3, sUpp[lg * J + jm], vL);
                        vR = fmaf(tl2, sLow[lg * J + jp], vR);
                        vR = fmaf(tl3, sUpp[lg * J + jp], vR);
                    }
                    const float m1 = u + vL + e1 + blo;
                    const float m2 = u + vR + e2 + blo;
                    const float res = p + buo + (h1m ? lrelu(m1) : 0.f) + (h2m ? lrelu(m2) : 0.f);
                    if (valid) {
                        const size_t node = baseNode + row;
                        const u16 hh = f2bf(res);
                        outHi[node * C_OUT + o] = hh;
                        outLo[node * C_OUT + o] = f2bf(res - bf2f(hh));
                    }
                }
            }
            Vpp = Vp; Vp = Vc; Up = Uc; Pp = Pc;
        }
    }
}

// ---------------------------------------------------------------------------
// enc1: v2 FMA block (C_IN=3), writes split-bf16 padded to OPAD.
template<int C_IN, int C_OUT, int C_E, int J, int NN, int OPAD>
__global__ __launch_bounds__(256)
void block_small(const float* __restrict__ xA, const float* __restrict__ xB, int node_half,
                 const float* __restrict__ eaA, const float* __restrict__ eaB, int g_half,
                 const float* __restrict__ Wl, const float* __restrict__ bl,
                 const float* __restrict__ Wu, const float* __restrict__ bu,
                 u16* __restrict__ outHi, u16* __restrict__ outLo, int N)
{
    constexpr int CTOT = 2 * C_IN + C_E;
    constexpr int SOP = C_OUT + 1;
    constexpr int NPB = 256 / C_OUT;
    __shared__ float wl_T[CTOT * SOP];
    __shared__ float wu_T[C_IN * SOP];
    __shared__ float bl_s[C_OUT], bu_s[C_OUT];
    const int t = threadIdx.x;
    for (int i = t; i < C_OUT * CTOT; i += 256) { int oo = i / CTOT, kk = i % CTOT; wl_T[kk * SOP + oo] = Wl[i]; }
    for (int i = t; i < C_OUT * C_IN; i += 256) { int oo = i / C_IN, kk = i % C_IN; wu_T[kk * SOP + oo] = Wu[i]; }
    if (t < C_OUT) { bl_s[t] = bl[t]; bu_s[t] = bu[t]; }
    __syncthreads();

    const int o = t % C_OUT;
    const int s = t / C_OUT;
    const int nb = (blockIdx.x * NPB + s) * NN;
    float up[NN], m1[NN], m2[NN];
    #pragma unroll
    for (int i = 0; i < NN; ++i) { up[i] = bu_s[o]; m1[i] = bl_s[o]; m2[i] = bl_s[o]; }
    auto clampn = [&](int nd) { return nd < 0 ? 0 : (nd >= N ? N - 1 : nd); };

    for (int k = 0; k < C_IN; ++k) {
        const float w0 = wl_T[k * SOP + o];
        const float w1 = wl_T[(C_IN + k) * SOP + o];
        const float wuv = wu_T[k * SOP + o];
        float xs[NN + 2];
        #pragma unroll
        for (int i = 0; i < NN + 2; ++i) {
            const int nd = clampn(nb - 1 + i);
            xs[i] = (nd < node_half) ? xA[(size_t)nd * C_IN + k]
                                     : xB[(size_t)(nd - node_half) * C_IN + k];
        }
        #pragma unroll
        for (int nd = 0; nd < NN; ++nd) {
            up[nd] = fmaf(wuv, xs[nd + 1], up[nd]);
            m1[nd] = fmaf(w0, xs[nd + 1], m1[nd]);
            m1[nd] = fmaf(w1, xs[nd], m1[nd]);
            m2[nd] = fmaf(w0, xs[nd + 1], m2[nd]);
            m2[nd] = fmaf(w1, xs[nd + 2], m2[nd]);
        }
    }
    #pragma unroll
    for (int nd = 0; nd < NN; ++nd) {
        const int node = nb + nd;
        const int g = node / J;
        const int j = node - g * J;
        const bool has1 = (j > 0), has2 = (j < J - 1);
        const int geff = (g < g_half) ? g : g - g_half;
        const float* ea = (g < g_half) ? eaA : eaB;
        const ptrdiff_t e1 = ((ptrdiff_t)geff * 2 * (J - 1) + (j - 1)) * C_E;
        const ptrdiff_t e2 = ((ptrdiff_t)geff * 2 * (J - 1) + (J - 1) + j) * C_E;
        float a1 = m1[nd], a2 = m2[nd];
        #pragma unroll
        for (int k = 0; k < C_E; ++k) {
            const float w = wl_T[(2 * C_IN + k) * SOP + o];
            if (has1) a1 = fmaf(w, ea[e1 + k], a1);
            if (has2) a2 = fmaf(w, ea[e2 + k], a2);
        }
        const float v = up[nd] + (has1 ? lrelu(a1) : 0.f) + (has2 ? lrelu(a2) : 0.f);
        const u16 hh = f2bf(v);
        outHi[(size_t)node * OPAD + o] = hh;
        outLo[(size_t)node * OPAD + o] = f2bf(v - bf2f(hh));
        if (OPAD > C_OUT) {
            outHi[(size_t)node * OPAD + o + C_OUT] = 0;
            outLo[(size_t)node * OPAD + o + C_OUT] = 0;
        }
    }
}

// ---------------------------------------------------------------------------
// trans v3 (LEDGER D6): A frags DIRECT from global; LDS only for W tile.
__device__ __forceinline__ void trans_step(const u16* __restrict__ sWHb,
                                           const u16* __restrict__ sWLb,
                                           const u16x8* __restrict__ a,
                                           int wn, int lr, int kg, f32x4 acc[4][2])
{
    bf16x8 bh[2], bl2[2];
    #pragma unroll
    for (int n = 0; n < 2; ++n) {
        const int r = wn * 32 + n * 16 + lr;
        bh[n]  = *(const bf16x8*)&sWHb[r * 40 + kg * 8];
        bl2[n] = *(const bf16x8*)&sWLb[r * 40 + kg * 8];
    }
    #pragma unroll
    for (int m = 0; m < 4; ++m) {
        const bf16x8 ah = __builtin_bit_cast(bf16x8, a[2 * m]);
        const bf16x8 al = __builtin_bit_cast(bf16x8, a[2 * m + 1]);
        #pragma unroll
        for (int n = 0; n < 2; ++n) {
            acc[m][n] = __builtin_amdgcn_mfma_f32_16x16x32_bf16(ah, bh[n],  acc[m][n], 0, 0, 0);
            acc[m][n] = __builtin_amdgcn_mfma_f32_16x16x32_bf16(ah, bl2[n], acc[m][n], 0, 0, 0);
            acc[m][n] = __builtin_amdgcn_mfma_f32_16x16x32_bf16(al, bh[n],  acc[m][n], 0, 0, 0);
        }
    }
}

__global__ __launch_bounds__(256)
void trans_mfma(const u16* __restrict__ aHi, const u16* __restrict__ aLo,
                const float* __restrict__ W, const float* __restrict__ bias,
                u16* __restrict__ zHi, u16* __restrict__ zLo)
{
    constexpr int NI = K_TR / 32;            // 34 (even)
    __shared__ __align__(16) u16 sWH[2][64 * 40], sWL[2][64 * 40];
    const int t = threadIdx.x, lane = t & 63, w = t >> 6;
    const int wm = w >> 1, wn = w & 1, lr = lane & 15, kg = lane >> 4;
    const int bm = blockIdx.x * 128, bn = blockIdx.y * 64;
    const int swr = t >> 2, swc = (t & 3) * 8;

    auto stageW = [&](int i, int buf) {
        const int k0 = i * 32;
        const float4 f0 = *(const float4*)&W[(size_t)(bn + swr) * K_TR + k0 + swc];
        const float4 f1 = *(const float4*)&W[(size_t)(bn + swr) * K_TR + k0 + swc + 4];
        const float fv[8] = {f0.x, f0.y, f0.z, f0.w, f1.x, f1.y, f1.z, f1.w};
        u16x8 hq, lq;
        #pragma unroll
        for (int j = 0; j < 8; ++j) {
            const u16 h = f2bf(fv[j]);
            hq[j] = h;
            lq[j] = f2bf(fv[j] - bf2f(h));
        }
        *(u16x8*)&sWH[buf][swr * 40 + swc] = hq;
        *(u16x8*)&sWL[buf][swr * 40 + swc] = lq;
    };
    u16x8 aA[8], aB[8];
    auto gloadA = [&](int i, u16x8* dst) {
        const int k0 = i * 32;
        #pragma unroll
        for (int m = 0; m < 4; ++m) {
            const size_t off = (size_t)(bm + wm * 64 + m * 16 + lr) * K_TR + k0 + kg * 8;
            dst[2 * m]     = *(const u16x8*)&aHi[off];
            dst[2 * m + 1] = *(const u16x8*)&aLo[off];
        }
    };

    f32x4 acc[4][2];
    #pragma unroll
    for (int m = 0; m < 4; ++m)
        #pragma unroll
        for (int n = 0; n < 2; ++n) acc[m][n] = f32x4{0.f, 0.f, 0.f, 0.f};

    stageW(0, 0);
    gloadA(0, aA);
    __syncthreads();
    for (int i = 0; i < NI; i += 2) {                 // NI even: no tail
        if (i + 1 < NI) { stageW(i + 1, 1); gloadA(i + 1, aB); }
        trans_step(sWH[0], sWL[0], aA, wn, lr, kg, acc);
        __syncthreads();
        if (i + 2 < NI) { stageW(i + 2, 0); gloadA(i + 2, aA); }
        trans_step(sWH[1], sWL[1], aB, wn, lr, kg, acc);
        __syncthreads();
    }

    #pragma unroll
    for (int n = 0; n < 2; ++n) {
        const int colz = bn + wn * 32 + n * 16 + lr;
        const float bv = bias[colz];
        #pragma unroll
        for (int m = 0; m < 4; ++m)
            #pragma unroll
            for (int r = 0; r < 4; ++r) {
                const int row = bm + wm * 64 + m * 16 + kg * 4 + r;
                const float v = tanhf(acc[m][n][r] + bv);
                const size_t idx = (size_t)row * N_TR + colz;
                const u16 hh = f2bf(v);
                zHi[idx] = hh;
                zLo[idx] = f2bf(v - bf2f(hh));
            }
    }
}

// ---------------------------------------------------------------------------
// dec3 + FK fused (LEDGER D7): 1 thread = 1 graph; rolling 3-row window.
__global__ __launch_bounds__(256)
void dec3fk_kernel(const u16* __restrict__ xHi, const u16* __restrict__ xLo,
                   const float* __restrict__ ea,
                   const float* __restrict__ Wl, const float* __restrict__ bl,
                   const float* __restrict__ Wu, const float* __restrict__ bu,
                   const float* __restrict__ lowv, const float* __restrict__ upv,
                   const float* __restrict__ offset, const float* __restrict__ axis,
                   float* __restrict__ dout)
{
    const int g2 = blockIdx.x * 256 + threadIdx.x;
    if (g2 >= G2) return;
    const int geff = (g2 >= G_NUM) ? g2 - G_NUM : g2;
    const bool rightH = (g2 >= G_NUM);

    auto loadrow = [&](int nd, float* x) {
        const u16x8 h0 = *(const u16x8*)&xHi[(size_t)nd * 16];
        const u16x8 h1 = *(const u16x8*)&xHi[(size_t)nd * 16 + 8];
        const u16x8 l0 = *(const u16x8*)&xLo[(size_t)nd * 16];
        const u16x8 l1 = *(const u16x8*)&xLo[(size_t)nd * 16 + 8];
        #pragma unroll
        for (int k = 0; k < 8; ++k) {
            x[k]     = bf2f(h0[k]) + bf2f(l0[k]);
            x[k + 8] = bf2f(h1[k]) + bf2f(l1[k]);
        }
    };

    float xprev[16], xcur[16], xnext[16];
    #pragma unroll
    for (int k = 0; k < 16; ++k) xprev[k] = 0.f;
    loadrow(g2 * JT, xcur);
    loadrow(g2 * JT + 1, xnext);

    float R[9];
    float px = 0.f, py = 0.f, pz = 0.f;
    for (int j = 0; j < JT; ++j) {
        const int node = g2 * JT + j;
        const bool has1 = (j > 0), has2 = (j < JT - 1);
        float m1 = bl[0], m2 = m1, up = bu[0];
        #pragma unroll
        for (int k = 0; k < 16; ++k) {
            const float xd = xcur[k];
            up = fmaf(Wu[k], xd, up);
            const float w0 = Wl[k];
            m1 = fmaf(w0, xd, m1);
            m2 = fmaf(w0, xd, m2);
            const float w1 = Wl[16 + k];
            m1 = fmaf(w1, xprev[k], m1);
            m2 = fmaf(w1, xnext[k], m2);
        }
        const int e1 = (geff * 24 + (j - 1)) * 6;
        const int e2 = (geff * 24 + 12 + j) * 6;
        #pragma unroll
        for (int k = 0; k < 6; ++k) {
            const float ww = Wl[32 + k];
            if (has1) m1 = fmaf(ww, ea[e1 + k], m1);
            if (has2) m2 = fmaf(ww, ea[e2 + k], m2);
        }
        const float v = up + (has1 ? lrelu(m1) : 0.f) + (has2 ? lrelu(m2) : 0.f);
        const int idx = geff * JT + j;
        const float lo = lowv[idx], hi = upv[idx];
        const float a = lo + (hi - lo) * (tanhf(v) + 1.f) * 0.5f;
        if (!rightH) dout[node] = a;
        else         dout[4 * HN + idx] = a;

        // FK step
        const float ax = axis[idx * 3], ay = axis[idx * 3 + 1], az = axis[idx * 3 + 2];
        const float ox = offset[idx * 3], oy = offset[idx * 3 + 1], oz = offset[idx * 3 + 2];
        const float c = cosf(a), s = sinf(a), ic = 1.f - c;
        const float L[9] = {
            c + ic * ax * ax,      ic * ax * ay - s * az, ic * ax * az + s * ay,
            ic * ay * ax + s * az, c + ic * ay * ay,      ic * ay * az - s * ax,
            ic * az * ax - s * ay, ic * az * ay + s * ax, c + ic * az * az };
        if (j == 0) {
            px = ox; py = oy; pz = oz;
            #pragma unroll
            for (int q = 0; q < 9; ++q) R[q] = L[q];
        } else {
            px += R[0] * ox + R[1] * oy + R[2] * oz;
            py += R[3] * ox + R[4] * oy + R[5] * oz;
            pz += R[6] * ox + R[7] * oy + R[8] * oz;
            float T[9];
            #pragma unroll
            for (int r = 0; r < 3; ++r)
                #pragma unroll
                for (int cc = 0; cc < 3; ++cc)
                    T[r * 3 + cc] = R[r * 3] * L[cc] + R[r * 3 + 1] * L[3 + cc] + R[r * 3 + 2] * L[6 + cc];
            #pragma unroll
            for (int q = 0; q < 9; ++q) R[q] = T[q];
        }
        const int pbase = (!rightH) ? (HN + node * 3) : (5 * HN + idx * 3);
        dout[pbase] = px; dout[pbase + 1] = py; dout[pbase + 2] = pz;

        // roll window
        #pragma unroll
        for (int k = 0; k < 16; ++k) { xprev[k] = xcur[k]; xcur[k] = xnext[k]; }
        const int nn = node + 2 < N_DEC ? node + 2 : N_DEC - 1;
        if (j < JT - 1) loadrow(nn, xnext);
    }
}

extern "C" void kernel_launch(void* const* d_in, const int* in_sizes, int n_in,
                              void* d_out, int out_size, void* d_ws, size_t ws_size,
                              hipStream_t stream)
{
    const float* l_x  = (const float*)d_in[0];
    const float* r_x  = (const float*)d_in[1];
    const float* l_ea = (const float*)d_in[4];
    const float* r_ea = (const float*)d_in[5];
    const float* ea_t = (const float*)d_in[7];
    const float* lowv = (const float*)d_in[8];
    const float* upv  = (const float*)d_in[9];
    const float* offs = (const float*)d_in[10];
    const float* axis = (const float*)d_in[11];
    const float* e1lW = (const float*)d_in[14]; const float* e1lB = (const float*)d_in[15];
    const float* e1uW = (const float*)d_in[16]; const float* e1uB = (const float*)d_in[17];
    const float* e2lW = (const float*)d_in[18]; const float* e2lB = (const float*)d_in[19];
    const float* e2uW = (const float*)d_in[20]; const float* e2uB = (const float*)d_in[21];
    const float* e3lW = (const float*)d_in[22]; const float* e3lB = (const float*)d_in[23];
    const float* e3uW = (const float*)d_in[24]; const float* e3uB = (const float*)d_in[25];
    const float* trW  = (const float*)d_in[26]; const float* trB  = (const float*)d_in[27];
    const float* d1lW = (const float*)d_in[28]; const float* d1lB = (const float*)d_in[29];
    const float* d1uW = (const float*)d_in[30]; const float* d1uB = (const float*)d_in[31];
    const float* d2lW = (const float*)d_in[32]; const float* d2lB = (const float*)d_in[33];
    const float* d2uW = (const float*)d_in[34]; const float* d2uB = (const float*)d_in[35];
    const float* d3lW = (const float*)d_in[36]; const float* d3lB = (const float*)d_in[37];
    const float* d3uW = (const float*)d_in[38]; const float* d3uB = (const float*)d_in[39];

    // ws map (LEDGER D3): peak 125,829,120 B, all buffers split-bf16 hi|lo.
    char* ws = (char*)d_ws;
    u16* h1H  = (u16*)(ws + 0);          u16* h1L  = (u16*)(ws + 17825792);
    u16* h2H  = (u16*)(ws + 71303168);   u16* h2L  = (u16*)(ws + 89128960);
    u16* aH   = (u16*)(ws + 0);          u16* aL   = (u16*)(ws + 35651584);
    u16* zzH  = (u16*)(ws + 71303168);   u16* zzL  = (u16*)(ws + 98566144);
    u16* hd1H = (u16*)(ws + 0);          u16* hd1L = (u16*)(ws + 13631488);
    u16* hd2H = (u16*)(ws + 27262976);   u16* hd2L = (u16*)(ws + 34078720);
    float* outp = (float*)d_out;

    block_small<3, 16, 3, JS, 4, 32><<<N_ENC / 64, 256, 0, stream>>>(
        l_x, r_x, G_NUM * JS, l_ea, r_ea, G_NUM,
        e1lW, e1lB, e1uW, e1uB, h1H, h1L, N_ENC);
    block_mfma<32, 16, 32, 3, JS, 4, false><<<1024, 256, 0, stream>>>(
        h1H, h1L, l_ea, r_ea, G_NUM, nullptr, nullptr,
        e2lW, e2lB, e2uW, e2uB, h2H, h2L);
    block_mfma<32, 32, 64, 3, JS, 4, false><<<1024, 256, 0, stream>>>(
        h2H, h2L, l_ea, r_ea, G_NUM, nullptr, nullptr,
        e3lW, e3lB, e3uW, e3uB, aH, aL);
    trans_mfma<<<dim3(G2 / 128, N_TR / 64), 256, 0, stream>>>(aH, aL, trW, trB, zzH, zzL);
    block_mfma<64, 66, 32, 6, JT, 4, true><<<1024, 256, 0, stream>>>(
        zzH, zzL, ea_t, ea_t, G_NUM, lowv, upv,
        d1lW, d1lB, d1uW, d1uB, hd1H, hd1L);
    block_mfma<32, 32, 16, 6, JT, 4, false><<<1024, 256, 0, stream>>>(
        hd1H, hd1L, ea_t, ea_t, G_NUM, nullptr, nullptr,
        d2lW, d2lB, d2uW, d2uB, hd2H, hd2L);
    dec3fk_kernel<<<(G2 + 255) / 256, 256, 0, stream>>>(
        hd2H, hd2L, ea_t, d3lW, d3lB, d3uW, d3uB, lowv, upv, offs, axis, outp);
}

// Round 7
// 527.048 us; speedup vs baseline: 1.2025x; 1.2025x over previous
//
#include <hip/hip_runtime.h>
#include <math.h>

// ============================ RELAY LEDGER =================================
// FACTS (hardware-proven, don't re-derive)
//  F1 clocks vary per container hold (same src: 609 vs 1079 us). Compare
//     SHARES within a run, never absolute us across runs.
//  F2 absmax = 0.00390625 in every passing run (f32 AND split-bf16) ->
//     split-bf16 (hh+hl+lh, err ~2^-16) is numerically free. Keep 3 products
//     (dropping lh/hl loses 2^-9 rel = bf16-grade, defeats the split).
//  F3 PROVEN mfma_f32_16x16x32_bf16 layouts (R4/R5 end-to-end):
//     A/B frag: elem j of lane = M[row|col = lane&15][k = (lane>>4)*8 + j]
//     C/D: col = lane&15, row = (lane>>4)*4 + reg.
//  F4 R5 shares: trans 150us @ MfmaUtil 24% with staged-LDS A, 4x2 frags.
//  F5 kernel id by LDS_Block_Size (1024-gran) when names collide.
//  F6 R6: trans v3 (A frags DIRECT from global, 2-deep reg prefetch)
//     REGRESSED 150->287us, MfmaUtil 24->13. L2 latency not hideable with
//     depth-2; LDS staging of A is REQUIRED. D6 reverted.
//  F7 one dec1 dispatch = 22ms in PROFILED run only (timed total excludes
//     it) -> profiler outlier/preemption. If dec1 goes hot in timed runs,
//     its VGPR=248 is the suspect (2 waves/SIMD cap).
// DECISIONS
//  D3 ws map unchanged (peak 125,829,120 B proven).
//  D4 block_mfma: x frags direct from global is FINE there (weights in regs,
//     many waves, no LDS dependency chain). Don't confuse with F6.
//  D7 dec3+fk fused (proven R6, stayed out of top-5).
//  D8 trans v4 (this round): staged dbuf LDS for A AND W-split (80KB,
//     2 blk/CU), 128x128 tile, 4 waves 2x2, 4x4 frags/wave, 1 barrier/iter,
//     order = gload(i+1) -> step(i) -> stage(i+1) (T14). Read:MFMA cycle
//     ratio 192:240 (was 144:120). bn=6 tile: W rows clamped to 831, col
//     writes guarded < 832. FALLBACK if VGPR>256/spill: 4x2 frags BN=64.
// NEXT: if trans lands ~100us: remaining shares ~ enc3/dec1 blocks (~60-90us
//     each R4-clock) -> consider C_OUT-chunk parallelism (grid.y over ch) or
//     reduced VGPR; dec1 22ms watch (F7).
// ===========================================================================

constexpr int G_NUM = 8192;
constexpr int JS = 17;
constexpr int JT = 13;
constexpr int N_ENC = 2 * G_NUM * JS;
constexpr int N_DEC = 2 * G_NUM * JT;
constexpr int G2 = 2 * G_NUM;
constexpr int HN = G_NUM * JT;
constexpr int K_TR = JS * 64;            // 1088
constexpr int N_TR = JT * 64;            // 832

typedef unsigned short u16;
typedef u16   u16x8 __attribute__((ext_vector_type(8)));
typedef u16   u16x4 __attribute__((ext_vector_type(4)));
typedef float f32x4 __attribute__((ext_vector_type(4)));
typedef __bf16 bf16x8 __attribute__((ext_vector_type(8)));

__device__ __forceinline__ float lrelu(float v) { return v > 0.f ? v : 0.01f * v; }
__device__ __forceinline__ u16 f2bf(float f) {
    unsigned u = __float_as_uint(f);
    u += 0x7fff + ((u >> 16) & 1);
    return (u16)(u >> 16);
}
__device__ __forceinline__ float bf2f(u16 h) { return __uint_as_float((unsigned)h << 16); }

// ---------------------------------------------------------------------------
// block_mfma: whole SpatialBasicBlock on matrix cores (split-bf16 in/out).
template<int K_MM, int C_IN_W, int C_OUT, int C_E, int J, int G, bool TAIL>
__global__ __launch_bounds__(256)
void block_mfma(const u16* __restrict__ xHi, const u16* __restrict__ xLo,
                const float* __restrict__ eaA, const float* __restrict__ eaB, int g_half,
                const float* __restrict__ lowv, const float* __restrict__ upv,
                const float* __restrict__ Wl, const float* __restrict__ bl,
                const float* __restrict__ Wu, const float* __restrict__ bu,
                u16* __restrict__ outHi, u16* __restrict__ outLo)
{
    constexpr int ROWS = G * J;
    constexpr int F = (ROWS + 15) / 16;
    constexpr int NCH = C_OUT / 16;
    constexpr int KF = K_MM / 32;
    constexpr int KPAD = K_MM + 8;
    constexpr int EAS = 2 * (J - 1) * C_E;
    constexpr int CTOT = 2 * C_IN_W + C_E;
    constexpr int CW = (C_IN_W < K_MM) ? C_IN_W : K_MM;
    constexpr int WGG = 4 * G;

    __shared__ __align__(16) u16 sWH[3 * C_OUT * KPAD], sWL[3 * C_OUT * KPAD];
    __shared__ float sEA[WGG * EAS];
    __shared__ float sWe[C_OUT * C_E];
    __shared__ float sBl[C_OUT], sBu[C_OUT];
    __shared__ float sTl[TAIL ? 6 * C_OUT : 1];
    __shared__ float sLow[TAIL ? WGG * J : 1], sUpp[TAIL ? WGG * J : 1];

    const int t = threadIdx.x;
    const int g0 = blockIdx.x * WGG;

    for (int i = t; i < 3 * C_OUT * K_MM; i += 256) {
        const int ch = i / K_MM, k = i % K_MM;
        const int p = ch / C_OUT, o = ch % C_OUT;
        float v = 0.f;
        if (k < CW) {
            if (p == 0)      v = Wl[o * CTOT + k];
            else if (p == 1) v = Wl[o * CTOT + C_IN_W + k];
            else             v = Wu[o * C_IN_W + k];
        }
        const u16 h = f2bf(v);
        sWH[ch * KPAD + k] = h;
        sWL[ch * KPAD + k] = f2bf(v - bf2f(h));
    }
    for (int i = t; i < WGG * EAS; i += 256) {
        const int lg = i / EAS, r = i % EAS;
        const int g = g0 + lg;
        sEA[i] = (g < g_half) ? eaA[(size_t)g * EAS + r]
                              : eaB[(size_t)(g - g_half) * EAS + r];
    }
    for (int i = t; i < C_OUT * C_E; i += 256)
        sWe[i] = Wl[(i / C_E) * CTOT + 2 * C_IN_W + (i % C_E)];
    if (t < C_OUT) { sBl[t] = bl[t]; sBu[t] = bu[t]; }
    if constexpr (TAIL) {
        if (t < C_OUT) {
            sTl[t * 6 + 0] = Wl[t * CTOT + K_MM];
            sTl[t * 6 + 1] = Wl[t * CTOT + K_MM + 1];
            sTl[t * 6 + 2] = Wl[t * CTOT + C_IN_W + K_MM];
            sTl[t * 6 + 3] = Wl[t * CTOT + C_IN_W + K_MM + 1];
            sTl[t * 6 + 4] = Wu[t * C_IN_W + K_MM];
            sTl[t * 6 + 5] = Wu[t * C_IN_W + K_MM + 1];
        }
        for (int i = t; i < WGG * J; i += 256) {
            const int lg = i / J, j = i % J;
            const int g = g0 + lg;
            const int ge = (g < g_half) ? g : g - g_half;
            sLow[i] = lowv[ge * J + j];
            sUpp[i] = upv[ge * J + j];
        }
    }
    __syncthreads();

    const int wv = t >> 6, lane = t & 63;
    const int col = lane & 15, kg = lane >> 4;
    const size_t baseNode = (size_t)(blockIdx.x * 4 + wv) * ROWS;
    const int lgB = wv * G;

    for (int ch = 0; ch < NCH; ++ch) {
        const int o = ch * 16 + col;
        bf16x8 wUh[KF], wUl[KF], wVh[KF], wVl[KF], wPh[KF], wPl[KF];
        #pragma unroll
        for (int kf = 0; kf < KF; ++kf) {
            wUh[kf] = *(const bf16x8*)&sWH[(0 * C_OUT + o) * KPAD + kf * 32 + kg * 8];
            wUl[kf] = *(const bf16x8*)&sWL[(0 * C_OUT + o) * KPAD + kf * 32 + kg * 8];
            wVh[kf] = *(const bf16x8*)&sWH[(1 * C_OUT + o) * KPAD + kf * 32 + kg * 8];
            wVl[kf] = *(const bf16x8*)&sWL[(1 * C_OUT + o) * KPAD + kf * 32 + kg * 8];
            wPh[kf] = *(const bf16x8*)&sWH[(2 * C_OUT + o) * KPAD + kf * 32 + kg * 8];
            wPl[kf] = *(const bf16x8*)&sWL[(2 * C_OUT + o) * KPAD + kf * 32 + kg * 8];
        }
        float we[C_E];
        #pragma unroll
        for (int k = 0; k < C_E; ++k) we[k] = sWe[o * C_E + k];
        const float blo = sBl[o], buo = sBu[o];
        float tl0 = 0, tl1 = 0, tl2 = 0, tl3 = 0, tl4 = 0, tl5 = 0;
        if constexpr (TAIL) {
            tl0 = sTl[o * 6 + 0]; tl1 = sTl[o * 6 + 1]; tl2 = sTl[o * 6 + 2];
            tl3 = sTl[o * 6 + 3]; tl4 = sTl[o * 6 + 4]; tl5 = sTl[o * 6 + 5];
        }

        f32x4 Vpp = {0,0,0,0}, Vp = {0,0,0,0};
        f32x4 Up = {0,0,0,0}, Pp = {0,0,0,0};
        #pragma unroll
        for (int f = 0; f <= F; ++f) {
            f32x4 Vc = {0,0,0,0}, Uc = {0,0,0,0}, Pc = {0,0,0,0};
            if (f < F) {
                const int nrow = f * 16 + col;
                const size_t nd = baseNode + (nrow < ROWS ? nrow : ROWS - 1);
                #pragma unroll
                for (int kf = 0; kf < KF; ++kf) {
                    const bf16x8 aH = *(const bf16x8*)&xHi[nd * K_MM + kf * 32 + kg * 8];
                    const bf16x8 aL = *(const bf16x8*)&xLo[nd * K_MM + kf * 32 + kg * 8];
                    Vc = __builtin_amdgcn_mfma_f32_16x16x32_bf16(aH, wVh[kf], Vc, 0, 0, 0);
                    Vc = __builtin_amdgcn_mfma_f32_16x16x32_bf16(aH, wVl[kf], Vc, 0, 0, 0);
                    Vc = __builtin_amdgcn_mfma_f32_16x16x32_bf16(aL, wVh[kf], Vc, 0, 0, 0);
                    Uc = __builtin_amdgcn_mfma_f32_16x16x32_bf16(aH, wUh[kf], Uc, 0, 0, 0);
                    Uc = __builtin_amdgcn_mfma_f32_16x16x32_bf16(aH, wUl[kf], Uc, 0, 0, 0);
                    Uc = __builtin_amdgcn_mfma_f32_16x16x32_bf16(aL, wUh[kf], Uc, 0, 0, 0);
                    Pc = __builtin_amdgcn_mfma_f32_16x16x32_bf16(aH, wPh[kf], Pc, 0, 0, 0);
                    Pc = __builtin_amdgcn_mfma_f32_16x16x32_bf16(aH, wPl[kf], Pc, 0, 0, 0);
                    Pc = __builtin_amdgcn_mfma_f32_16x16x32_bf16(aL, wPh[kf], Pc, 0, 0, 0);
                }
            }
            if (f >= 1) {
                const int fm = f - 1;
                const float vL0a = __shfl(Vpp[3], 48 + col);
                const float vL0b = __shfl(Vp[3], (lane - 16) & 63);
                const float vL0 = (kg == 0) ? vL0a : vL0b;
                const float vR3a = __shfl(Vc[0], col);
                const float vR3b = __shfl(Vp[0], (lane + 16) & 63);
                const float vR3 = (kg == 3) ? vR3a : vR3b;
                #pragma unroll
                for (int r = 0; r < 4; ++r) {
                    const int row = fm * 16 + kg * 4 + r;
                    const bool valid = row < ROWS;
                    const int jpos = row % J;
                    int gl = row / J; if (gl > G - 1) gl = G - 1;
                    const int lg = lgB + gl;
                    const bool h1m = valid && (jpos > 0);
                    const bool h2m = valid && (jpos < J - 1);
                    const int jm = jpos > 0 ? jpos - 1 : 0;
                    float e1 = 0.f, e2 = 0.f;
                    #pragma unroll
                    for (int k = 0; k < C_E; ++k) {
                        e1 = fmaf(we[k], sEA[lg * EAS + jm * C_E + k], e1);
                        e2 = fmaf(we[k], sEA[lg * EAS + (J - 1 + jpos) * C_E + k], e2);
                    }
                    float vL = (r == 0) ? vL0 : Vp[r - 1];
                    float vR = (r == 3) ? vR3 : Vp[r + 1];
                    float u = Up[r], p = Pp[r];
                    if constexpr (TAIL) {
                        const int jp = jpos < J - 1 ? jpos + 1 : J - 1;
                        u = fmaf(tl0, sLow[lg * J + jpos], u);
                        u = fmaf(tl1, sUpp[lg * J + jpos], u);
                        p = fmaf(tl4, sLow[lg * J + jpos], p);
                        p = fmaf(tl5, sUpp[lg * J + jpos], p);
                        vL = fmaf(tl2, sLow[lg * J + jm], vL);
                        vL = fmaf(tl3, sUpp[lg * J + jm], vL);
                        vR = fmaf(tl2, sLow[lg * J + jp], vR);
                        vR = fmaf(tl3, sUpp[lg * J + jp], vR);
                    }
                    const float m1 = u + vL + e1 + blo;
                    const float m2 = u + vR + e2 + blo;
                    const float res = p + buo + (h1m ? lrelu(m1) : 0.f) + (h2m ? lrelu(m2) : 0.f);
                    if (valid) {
                        const size_t node = baseNode + row;
                        const u16 hh = f2bf(res);
                        outHi[node * C_OUT + o] = hh;
                        outLo[node * C_OUT + o] = f2bf(res - bf2f(hh));
                    }
                }
            }
            Vpp = Vp; Vp = Vc; Up = Uc; Pp = Pc;
        }
    }
}

// ---------------------------------------------------------------------------
// enc1: v2 FMA block (C_IN=3), writes split-bf16 padded to OPAD.
template<int C_IN, int C_OUT, int C_E, int J, int NN, int OPAD>
__global__ __launch_bounds__(256)
void block_small(const float* __restrict__ xA, const float* __restrict__ xB, int node_half,
                 const float* __restrict__ eaA, const float* __restrict__ eaB, int g_half,
                 const float* __restrict__ Wl, const float* __restrict__ bl,
                 const float* __restrict__ Wu, const float* __restrict__ bu,
                 u16* __restrict__ outHi, u16* __restrict__ outLo, int N)
{
    constexpr int CTOT = 2 * C_IN + C_E;
    constexpr int SOP = C_OUT + 1;
    constexpr int NPB = 256 / C_OUT;
    __shared__ float wl_T[CTOT * SOP];
    __shared__ float wu_T[C_IN * SOP];
    __shared__ float bl_s[C_OUT], bu_s[C_OUT];
    const int t = threadIdx.x;
    for (int i = t; i < C_OUT * CTOT; i += 256) { int oo = i / CTOT, kk = i % CTOT; wl_T[kk * SOP + oo] = Wl[i]; }
    for (int i = t; i < C_OUT * C_IN; i += 256) { int oo = i / C_IN, kk = i % C_IN; wu_T[kk * SOP + oo] = Wu[i]; }
    if (t < C_OUT) { bl_s[t] = bl[t]; bu_s[t] = bu[t]; }
    __syncthreads();

    const int o = t % C_OUT;
    const int s = t / C_OUT;
    const int nb = (blockIdx.x * NPB + s) * NN;
    float up[NN], m1[NN], m2[NN];
    #pragma unroll
    for (int i = 0; i < NN; ++i) { up[i] = bu_s[o]; m1[i] = bl_s[o]; m2[i] = bl_s[o]; }
    auto clampn = [&](int nd) { return nd < 0 ? 0 : (nd >= N ? N - 1 : nd); };

    for (int k = 0; k < C_IN; ++k) {
        const float w0 = wl_T[k * SOP + o];
        const float w1 = wl_T[(C_IN + k) * SOP + o];
        const float wuv = wu_T[k * SOP + o];
        float xs[NN + 2];
        #pragma unroll
        for (int i = 0; i < NN + 2; ++i) {
            const int nd = clampn(nb - 1 + i);
            xs[i] = (nd < node_half) ? xA[(size_t)nd * C_IN + k]
                                     : xB[(size_t)(nd - node_half) * C_IN + k];
        }
        #pragma unroll
        for (int nd = 0; nd < NN; ++nd) {
            up[nd] = fmaf(wuv, xs[nd + 1], up[nd]);
            m1[nd] = fmaf(w0, xs[nd + 1], m1[nd]);
            m1[nd] = fmaf(w1, xs[nd], m1[nd]);
            m2[nd] = fmaf(w0, xs[nd + 1], m2[nd]);
            m2[nd] = fmaf(w1, xs[nd + 2], m2[nd]);
        }
    }
    #pragma unroll
    for (int nd = 0; nd < NN; ++nd) {
        const int node = nb + nd;
        const int g = node / J;
        const int j = node - g * J;
        const bool has1 = (j > 0), has2 = (j < J - 1);
        const int geff = (g < g_half) ? g : g - g_half;
        const float* ea = (g < g_half) ? eaA : eaB;
        const ptrdiff_t e1 = ((ptrdiff_t)geff * 2 * (J - 1) + (j - 1)) * C_E;
        const ptrdiff_t e2 = ((ptrdiff_t)geff * 2 * (J - 1) + (J - 1) + j) * C_E;
        float a1 = m1[nd], a2 = m2[nd];
        #pragma unroll
        for (int k = 0; k < C_E; ++k) {
            const float w = wl_T[(2 * C_IN + k) * SOP + o];
            if (has1) a1 = fmaf(w, ea[e1 + k], a1);
            if (has2) a2 = fmaf(w, ea[e2 + k], a2);
        }
        const float v = up[nd] + (has1 ? lrelu(a1) : 0.f) + (has2 ? lrelu(a2) : 0.f);
        const u16 hh = f2bf(v);
        outHi[(size_t)node * OPAD + o] = hh;
        outLo[(size_t)node * OPAD + o] = f2bf(v - bf2f(hh));
        if (OPAD > C_OUT) {
            outHi[(size_t)node * OPAD + o + C_OUT] = 0;
            outLo[(size_t)node * OPAD + o + C_OUT] = 0;
        }
    }
}

// ---------------------------------------------------------------------------
// trans v4 (LEDGER D8): staged dbuf LDS for A and split-W; 128x128 tile,
// 4 waves 2x2, 4x4 frags/wave; gload -> step -> stage order; 1 barrier/iter.
__global__ __launch_bounds__(256)
void trans_mfma(const u16* __restrict__ aHi, const u16* __restrict__ aLo,
                const float* __restrict__ W, const float* __restrict__ bias,
                u16* __restrict__ zHi, u16* __restrict__ zLo)
{
    constexpr int NI = K_TR / 32;            // 34
    constexpr int ST = 40;                   // u16 stride (80 B): 16B-aligned, 2-way max (free)
    __shared__ __align__(16) u16 sAH[2][128 * ST], sAL[2][128 * ST];
    __shared__ __align__(16) u16 sBH[2][128 * ST], sBL[2][128 * ST];   // 80 KB total
    const int t = threadIdx.x, lane = t & 63, w = t >> 6;
    const int wm = w >> 1, wn = w & 1, lr = lane & 15, kg = lane >> 4;
    const int bm = blockIdx.x * 128, bn = blockIdx.y * 128;
    const int sr = t >> 1, sc = (t & 1) * 16;   // 128 rows, 2 thr/row, 16 u16 each

    u16x8 rA[4];
    float4 rW[4];
    auto gload = [&](int i) {
        const int k0 = i * 32;
        const size_t oa = (size_t)(bm + sr) * K_TR + k0 + sc;
        rA[0] = *(const u16x8*)&aHi[oa];
        rA[1] = *(const u16x8*)&aHi[oa + 8];
        rA[2] = *(const u16x8*)&aLo[oa];
        rA[3] = *(const u16x8*)&aLo[oa + 8];
        int wrow = bn + sr; if (wrow > N_TR - 1) wrow = N_TR - 1;   // bn=6 tail clamp
        const size_t ow = (size_t)wrow * K_TR + k0 + sc;
        rW[0] = *(const float4*)&W[ow];
        rW[1] = *(const float4*)&W[ow + 4];
        rW[2] = *(const float4*)&W[ow + 8];
        rW[3] = *(const float4*)&W[ow + 12];
    };
    auto stage = [&](int buf) {
        *(u16x8*)&sAH[buf][sr * ST + sc]     = rA[0];
        *(u16x8*)&sAH[buf][sr * ST + sc + 8] = rA[1];
        *(u16x8*)&sAL[buf][sr * ST + sc]     = rA[2];
        *(u16x8*)&sAL[buf][sr * ST + sc + 8] = rA[3];
        u16x8 hq0{}, lq0{}, hq1{}, lq1{};
        auto sp0 = [&](float f, int j) { const u16 h = f2bf(f); hq0[j] = h; lq0[j] = f2bf(f - bf2f(h)); };
        auto sp1 = [&](float f, int j) { const u16 h = f2bf(f); hq1[j] = h; lq1[j] = f2bf(f - bf2f(h)); };
        sp0(rW[0].x, 0); sp0(rW[0].y, 1); sp0(rW[0].z, 2); sp0(rW[0].w, 3);
        sp0(rW[1].x, 4); sp0(rW[1].y, 5); sp0(rW[1].z, 6); sp0(rW[1].w, 7);
        sp1(rW[2].x, 0); sp1(rW[2].y, 1); sp1(rW[2].z, 2); sp1(rW[2].w, 3);
        sp1(rW[3].x, 4); sp1(rW[3].y, 5); sp1(rW[3].z, 6); sp1(rW[3].w, 7);
        *(u16x8*)&sBH[buf][sr * ST + sc]     = hq0;
        *(u16x8*)&sBH[buf][sr * ST + sc + 8] = hq1;
        *(u16x8*)&sBL[buf][sr * ST + sc]     = lq0;
        *(u16x8*)&sBL[buf][sr * ST + sc + 8] = lq1;
    };

    f32x4 acc[4][4];
    #pragma unroll
    for (int m = 0; m < 4; ++m)
        #pragma unroll
        for (int n = 0; n < 4; ++n) acc[m][n] = f32x4{0.f, 0.f, 0.f, 0.f};

    auto step = [&](int buf) {
        bf16x8 ah[4], al[4], bh[4], bl2[4];
        #pragma unroll
        for (int m = 0; m < 4; ++m) {
            const int r = wm * 64 + m * 16 + lr;
            ah[m] = *(const bf16x8*)&sAH[buf][r * ST + kg * 8];
            al[m] = *(const bf16x8*)&sAL[buf][r * ST + kg * 8];
        }
        #pragma unroll
        for (int n = 0; n < 4; ++n) {
            const int r = wn * 64 + n * 16 + lr;
            bh[n]  = *(const bf16x8*)&sBH[buf][r * ST + kg * 8];
            bl2[n] = *(const bf16x8*)&sBL[buf][r * ST + kg * 8];
        }
        #pragma unroll
        for (int m = 0; m < 4; ++m)
            #pragma unroll
            for (int n = 0; n < 4; ++n) {
                acc[m][n] = __builtin_amdgcn_mfma_f32_16x16x32_bf16(ah[m], bh[n],  acc[m][n], 0, 0, 0);
                acc[m][n] = __builtin_amdgcn_mfma_f32_16x16x32_bf16(ah[m], bl2[n], acc[m][n], 0, 0, 0);
                acc[m][n] = __builtin_amdgcn_mfma_f32_16x16x32_bf16(al[m], bh[n],  acc[m][n], 0, 0, 0);
            }
    };

    gload(0);
    stage(0);
    __syncthreads();
    for (int i = 0; i < NI; ++i) {
        const int buf = i & 1;
        if (i + 1 < NI) gload(i + 1);    // issue early (T14)
        step(buf);                        // 48 MFMA hide the global latency
        if (i + 1 < NI) stage(buf ^ 1);  // write late (reads of buf^1 done at i-1 barrier)
        __syncthreads();
    }

    #pragma unroll
    for (int n = 0; n < 4; ++n) {
        const int colz = bn + wn * 64 + n * 16 + lr;
        if (colz < N_TR) {
            const float bv = bias[colz];
            #pragma unroll
            for (int m = 0; m < 4; ++m)
                #pragma unroll
                for (int r = 0; r < 4; ++r) {
                    const int row = bm + wm * 64 + m * 16 + kg * 4 + r;
                    const float v = tanhf(acc[m][n][r] + bv);
                    const size_t idx = (size_t)row * N_TR + colz;
                    const u16 hh = f2bf(v);
                    zHi[idx] = hh;
                    zLo[idx] = f2bf(v - bf2f(hh));
                }
        }
    }
}

// ---------------------------------------------------------------------------
// dec3 + FK fused (LEDGER D7): 1 thread = 1 graph; rolling 3-row window.
__global__ __launch_bounds__(256)
void dec3fk_kernel(const u16* __restrict__ xHi, const u16* __restrict__ xLo,
                   const float* __restrict__ ea,
                   const float* __restrict__ Wl, const float* __restrict__ bl,
                   const float* __restrict__ Wu, const float* __restrict__ bu,
                   const float* __restrict__ lowv, const float* __restrict__ upv,
                   const float* __restrict__ offset, const float* __restrict__ axis,
                   float* __restrict__ dout)
{
    const int g2 = blockIdx.x * 256 + threadIdx.x;
    if (g2 >= G2) return;
    const int geff = (g2 >= G_NUM) ? g2 - G_NUM : g2;
    const bool rightH = (g2 >= G_NUM);

    auto loadrow = [&](int nd, float* x) {
        const u16x8 h0 = *(const u16x8*)&xHi[(size_t)nd * 16];
        const u16x8 h1 = *(const u16x8*)&xHi[(size_t)nd * 16 + 8];
        const u16x8 l0 = *(const u16x8*)&xLo[(size_t)nd * 16];
        const u16x8 l1 = *(const u16x8*)&xLo[(size_t)nd * 16 + 8];
        #pragma unroll
        for (int k = 0; k < 8; ++k) {
            x[k]     = bf2f(h0[k]) + bf2f(l0[k]);
            x[k + 8] = bf2f(h1[k]) + bf2f(l1[k]);
        }
    };

    float xprev[16], xcur[16], xnext[16];
    #pragma unroll
    for (int k = 0; k < 16; ++k) xprev[k] = 0.f;
    loadrow(g2 * JT, xcur);
    loadrow(g2 * JT + 1, xnext);

    float R[9];
    float px = 0.f, py = 0.f, pz = 0.f;
    for (int j = 0; j < JT; ++j) {
        const int node = g2 * JT + j;
        const bool has1 = (j > 0), has2 = (j < JT - 1);
        float m1 = bl[0], m2 = m1, up = bu[0];
        #pragma unroll
        for (int k = 0; k < 16; ++k) {
            const float xd = xcur[k];
            up = fmaf(Wu[k], xd, up);
            const float w0 = Wl[k];
            m1 = fmaf(w0, xd, m1);
            m2 = fmaf(w0, xd, m2);
            const float w1 = Wl[16 + k];
            m1 = fmaf(w1, xprev[k], m1);
            m2 = fmaf(w1, xnext[k], m2);
        }
        const int e1 = (geff * 24 + (j - 1)) * 6;
        const int e2 = (geff * 24 + 12 + j) * 6;
        #pragma unroll
        for (int k = 0; k < 6; ++k) {
            const float ww = Wl[32 + k];
            if (has1) m1 = fmaf(ww, ea[e1 + k], m1);
            if (has2) m2 = fmaf(ww, ea[e2 + k], m2);
        }
        const float v = up + (has1 ? lrelu(m1) : 0.f) + (has2 ? lrelu(m2) : 0.f);
        const int idx = geff * JT + j;
        const float lo = lowv[idx], hi = upv[idx];
        const float a = lo + (hi - lo) * (tanhf(v) + 1.f) * 0.5f;
        if (!rightH) dout[node] = a;
        else         dout[4 * HN + idx] = a;

        const float ax = axis[idx * 3], ay = axis[idx * 3 + 1], az = axis[idx * 3 + 2];
        const float ox = offset[idx * 3], oy = offset[idx * 3 + 1], oz = offset[idx * 3 + 2];
        const float c = cosf(a), s = sinf(a), ic = 1.f - c;
        const float L[9] = {
            c + ic * ax * ax,      ic * ax * ay - s * az, ic * ax * az + s * ay,
            ic * ay * ax + s * az, c + ic * ay * ay,      ic * ay * az - s * ax,
            ic * az * ax - s * ay, ic * az * ay + s * ax, c + ic * az * az };
        if (j == 0) {
            px = ox; py = oy; pz = oz;
            #pragma unroll
            for (int q = 0; q < 9; ++q) R[q] = L[q];
        } else {
            px += R[0] * ox + R[1] * oy + R[2] * oz;
            py += R[3] * ox + R[4] * oy + R[5] * oz;
            pz += R[6] * ox + R[7] * oy + R[8] * oz;
            float T[9];
            #pragma unroll
            for (int r = 0; r < 3; ++r)
                #pragma unroll
                for (int cc = 0; cc < 3; ++cc)
                    T[r * 3 + cc] = R[r * 3] * L[cc] + R[r * 3 + 1] * L[3 + cc] + R[r * 3 + 2] * L[6 + cc];
            #pragma unroll
            for (int q = 0; q < 9; ++q) R[q] = T[q];
        }
        const int pbase = (!rightH) ? (HN + node * 3) : (5 * HN + idx * 3);
        dout[pbase] = px; dout[pbase + 1] = py; dout[pbase + 2] = pz;

        #pragma unroll
        for (int k = 0; k < 16; ++k) { xprev[k] = xcur[k]; xcur[k] = xnext[k]; }
        const int nn = node + 2 < N_DEC ? node + 2 : N_DEC - 1;
        if (j < JT - 1) loadrow(nn, xnext);
    }
}

extern "C" void kernel_launch(void* const* d_in, const int* in_sizes, int n_in,
                              void* d_out, int out_size, void* d_ws, size_t ws_size,
                              hipStream_t stream)
{
    const float* l_x  = (const float*)d_in[0];
    const float* r_x  = (const float*)d_in[1];
    const float* l_ea = (const float*)d_in[4];
    const float* r_ea = (const float*)d_in[5];
    const float* ea_t = (const float*)d_in[7];
    const float* lowv = (const float*)d_in[8];
    const float* upv  = (const float*)d_in[9];
    const float* offs = (const float*)d_in[10];
    const float* axis = (const float*)d_in[11];
    const float* e1lW = (const float*)d_in[14]; const float* e1lB = (const float*)d_in[15];
    const float* e1uW = (const float*)d_in[16]; const float* e1uB = (const float*)d_in[17];
    const float* e2lW = (const float*)d_in[18]; const float* e2lB = (const float*)d_in[19];
    const float* e2uW = (const float*)d_in[20]; const float* e2uB = (const float*)d_in[21];
    const float* e3lW = (const float*)d_in[22]; const float* e3lB = (const float*)d_in[23];
    const float* e3uW = (const float*)d_in[24]; const float* e3uB = (const float*)d_in[25];
    const float* trW  = (const float*)d_in[26]; const float* trB  = (const float*)d_in[27];
    const float* d1lW = (const float*)d_in[28]; const float* d1lB = (const float*)d_in[29];
    const float* d1uW = (const float*)d_in[30]; const float* d1uB = (const float*)d_in[31];
    const float* d2lW = (const float*)d_in[32]; const float* d2lB = (const float*)d_in[33];
    const float* d2uW = (const float*)d_in[34]; const float* d2uB = (const float*)d_in[35];
    const float* d3lW = (const float*)d_in[36]; const float* d3lB = (const float*)d_in[37];
    const float* d3uW = (const float*)d_in[38]; const float* d3uB = (const float*)d_in[39];

    // ws map (LEDGER D3): peak 125,829,120 B, all buffers split-bf16 hi|lo.
    char* ws = (char*)d_ws;
    u16* h1H  = (u16*)(ws + 0);          u16* h1L  = (u16*)(ws + 17825792);
    u16* h2H  = (u16*)(ws + 71303168);   u16* h2L  = (u16*)(ws + 89128960);
    u16* aH   = (u16*)(ws + 0);          u16* aL   = (u16*)(ws + 35651584);
    u16* zzH  = (u16*)(ws + 71303168);   u16* zzL  = (u16*)(ws + 98566144);
    u16* hd1H = (u16*)(ws + 0);          u16* hd1L = (u16*)(ws + 13631488);
    u16* hd2H = (u16*)(ws + 27262976);   u16* hd2L = (u16*)(ws + 34078720);
    float* outp = (float*)d_out;

    block_small<3, 16, 3, JS, 4, 32><<<N_ENC / 64, 256, 0, stream>>>(
        l_x, r_x, G_NUM * JS, l_ea, r_ea, G_NUM,
        e1lW, e1lB, e1uW, e1uB, h1H, h1L, N_ENC);
    block_mfma<32, 16, 32, 3, JS, 4, false><<<1024, 256, 0, stream>>>(
        h1H, h1L, l_ea, r_ea, G_NUM, nullptr, nullptr,
        e2lW, e2lB, e2uW, e2uB, h2H, h2L);
    block_mfma<32, 32, 64, 3, JS, 4, false><<<1024, 256, 0, stream>>>(
        h2H, h2L, l_ea, r_ea, G_NUM, nullptr, nullptr,
        e3lW, e3lB, e3uW, e3uB, aH, aL);
    trans_mfma<<<dim3(G2 / 128, (N_TR + 127) / 128), 256, 0, stream>>>(
        aH, aL, trW, trB, zzH, zzL);
    block_mfma<64, 66, 32, 6, JT, 4, true><<<1024, 256, 0, stream>>>(
        zzH, zzL, ea_t, ea_t, G_NUM, lowv, upv,
        d1lW, d1lB, d1uW, d1uB, hd1H, hd1L);
    block_mfma<32, 32, 16, 6, JT, 4, false><<<1024, 256, 0, stream>>>(
        hd1H, hd1L, ea_t, ea_t, G_NUM, nullptr, nullptr,
        d2lW, d2lB, d2uW, d2uB, hd2H, hd2L);
    dec3fk_kernel<<<(G2 + 255) / 256, 256, 0, stream>>>(
        hd2H, hd2L, ea_t, d3lW, d3lB, d3uW, d3uB, lowv, upv, offs, axis, outp);
}